// Round 18
// baseline (86.198 us; speedup 1.0000x reference)
//
#include <hip/hip_runtime.h>

typedef float f32x4 __attribute__((ext_vector_type(4)));
typedef __bf16 bf16x8 __attribute__((ext_vector_type(8)));
typedef unsigned short u16x8 __attribute__((ext_vector_type(8)));

__device__ __forceinline__ unsigned short f2bf(float f) {
  union { float f; unsigned u; } v; v.f = f;
  unsigned r = v.u + 0x7FFFu + ((v.u >> 16) & 1u);
  return (unsigned short)(r >> 16);
}
__device__ __forceinline__ float min3f(float a, float b, float c) {
  return fminf(fminf(a, b), c);
}
__device__ __forceinline__ float max3f(float a, float b, float c) {
  return fmaxf(fmaxf(a, b), c);
}
__device__ __forceinline__ float med3f(float a, float b, float c) {
  return __builtin_amdgcn_fmed3f(a, b, c);
}

// async global->LDS, 16B per lane, LDS dest = wave-uniform base + lane*16
__device__ __forceinline__ void gload_lds16(const void* g, void* l) {
  __builtin_amdgcn_global_load_lds(
      (const __attribute__((address_space(1))) void*)g,
      (__attribute__((address_space(3))) void*)l, 16, 0, 0);
}

// conv_w fp32 [256][256] -> bf16 in MFMA-fragment-linear order:
// wbf[((ks*16 + ob)*64 + lane)*8 + j] = bf16(W[ob*16 + (lane&15)][ks*32 + (lane>>4)*8 + j])
// (serves as the B-operand fragment: thread (g,l15) holds W[k=g*8+j][oc=ob*16+l15])
__global__ void wconv_k(const float* __restrict__ w, unsigned short* __restrict__ wbf) {
  int idx  = blockIdx.x * 256 + threadIdx.x;   // 0..8191
  int lane = idx & 63;
  int ob   = (idx >> 6) & 15;
  int ks   = idx >> 10;                        // 0..7
  int o = (ob << 4) + (lane & 15);
  int c = (ks << 5) + ((lane >> 4) << 3);
  const float* src = w + (o << 8) + c;
  f32x4 v0 = *(const f32x4*)src;
  f32x4 v1 = *(const f32x4*)(src + 4);
  u16x8 ov;
  ov[0] = f2bf(v0[0]); ov[1] = f2bf(v0[1]); ov[2] = f2bf(v0[2]); ov[3] = f2bf(v0[3]);
  ov[4] = f2bf(v1[0]); ov[5] = f2bf(v1[1]); ov[6] = f2bf(v1[2]); ov[7] = f2bf(v1[3]);
  *(u16x8*)(wbf + (idx << 3)) = ov;
}

// One block = (batch, row-pair). WAVE = px'-QUARTER x ALL 256 oc:
// wave w owns (row rw = r0+(w>>1), px in [32(w&1), 32(w&1)+32)).
// => medians, Bt med-tile, pa fragments all WAVE-PRIVATE (no Bt barrier);
// fold reads Xs[cur] which stage(ks+1) (-> Xs[nxt]) never touches.
// ONE __syncthreads per step (8 total): serves only the cross-wave Xs
// staging RAW/WAR, with full-median-phase latency cover for the stage.
__launch_bounds__(256, 2)
__global__ void fused_k(const float* __restrict__ x,
                        const unsigned short* __restrict__ wbf,
                        const float* __restrict__ bias,
                        float* __restrict__ out) {
  __shared__ float Xs[2][128][64];          // 64 KB: row = ch*4+dr, granule ^(ch&15)
  __shared__ unsigned short Bt[4][32][42];  // 10.5 KB wave-private med tiles (pad 42)

  const int t   = threadIdx.x;
  const int blk = blockIdx.x;
  const int swz = ((blk & 7) << 7) | (blk >> 3);   // XCD-bijective (1024 = 8*128)
  const int b   = swz >> 5;
  const int r0  = (swz & 31) << 1;
  const int lane = t & 63;
  const int w    = t >> 6;       // wave 0..3
  const int g    = lane >> 4;
  const int l15  = lane & 15;

  const int mc  = lane >> 1;     // median channel 0..31 (local)
  const int e   = lane & 1;      // 16-px half within the wave's 32-px window
  const int h   = w & 1;         // px-window: pw = 32h
  const int drb = w >> 1;        // staged-row base (rows rw-1..rw+1 = dr drb..drb+2)
  const int rw  = r0 + drb;      // wave's output row
  const bool zT = (rw == 0), zB = (rw == 63);

  const float* xb = x + ((size_t)b << 20);

  // stage: instr p stages channel cp = 8w+p (4 rows x 64 px = 1 KB),
  // granule pre-swizzled by ^(cp&15)
  unsigned soff[8];
  #pragma unroll
  for (int p = 0; p < 8; ++p) {
    int cp = (w << 3) + p;
    int gr = r0 + (lane >> 4) - 1;
    gr = gr < 0 ? 0 : (gr > 63 ? 63 : gr);   // clamp; zeroed in VALU at median
    int bG = (lane & 15) ^ (cp & 15);
    soff[p] = ((unsigned)cp << 14) + ((unsigned)gr << 8) + ((unsigned)bG << 4);
  }
  auto stage = [&](int step, int buf) {
    const unsigned kso = (unsigned)step << 19;   // step * 32ch * 16KB
    #pragma unroll
    for (int p = 0; p < 8; ++p)
      gload_lds16((const char*)xb + (soff[p] + kso), &Xs[buf][((w << 3) + p) << 2][0]);
  };

  f32x4 acc[2][16];                 // [d: px half-block][n: oc block] = 128 VGPR
  #pragma unroll
  for (int d = 0; d < 2; ++d)
    #pragma unroll
    for (int n = 0; n < 16; ++n)
      acc[d][n] = (f32x4){0.f, 0.f, 0.f, 0.f};

  stage(0, 0);
  __syncthreads();

  #pragma unroll
  for (int ks = 0; ks < 8; ++ks) {
    const int cur = ks & 1;

    // (1) stage next K-slice into the other buffer (cover = this whole step)
    if (ks < 7) stage(ks + 1, cur ^ 1);
    __builtin_amdgcn_sched_barrier(0);

    // (2) median source reads: 3 rows x 4 granules (16 px window)
    f32x4 va[3][4];
    const int gb = (h << 3) + (e << 2);
    #pragma unroll
    for (int dr = 0; dr < 3; ++dr) {
      const float* rp = &Xs[cur][(mc << 2) + drb + dr][0];
      #pragma unroll
      for (int k4 = 0; k4 < 4; ++k4)
        va[dr][k4] = *(const f32x4*)(rp + (((gb + k4) ^ (mc & 15)) << 2));
    }
    // edges: outer from staged halo (px31 / px32), inner via shfl_xor(1)
    float eL[3], eR[3];
    #pragma unroll
    for (int dr = 0; dr < 3; ++dr) {
      const float* rp = &Xs[cur][(mc << 2) + drb + dr][0];
      float lv = rp[((7 ^ (mc & 15)) << 2) + 3];   // global px 31 (for h=1 left)
      float rv = rp[((8 ^ (mc & 15)) << 2) + 0];   // global px 32 (for h=0 right)
      float lo = h ? lv : 0.f;                     // W=-1
      float ro = h ? 0.f : rv;                     // W=32
      float shA = __shfl_xor(va[dr][0][0], 1);     // e=0 receives W16
      float shB = __shfl_xor(va[dr][3][3], 1);     // e=1 receives W15
      eL[dr] = e ? shB : lo;
      eR[dr] = e ? ro : shA;
    }
    if (zT) {
      #pragma unroll
      for (int k4 = 0; k4 < 4; ++k4) va[0][k4] = (f32x4){0.f, 0.f, 0.f, 0.f};
      eL[0] = 0.f; eR[0] = 0.f;
    }
    if (zB) {
      #pragma unroll
      for (int k4 = 0; k4 < 4; ++k4) va[2][k4] = (f32x4){0.f, 0.f, 0.f, 0.f};
      eL[2] = 0.f; eR[2] = 0.f;
    }

    // (3) medians via shared column triplets, two 8-px halves
    //     col L (0..17) = W 16e+L-1; median k: cols L=k..k+2
#define COLV(DR, L) ((L) == 0 ? eL[DR] : ((L) == 17 ? eR[DR] : va[DR][((L)-1) >> 2][((L)-1) & 3]))
    #pragma unroll
    for (int hs = 0; hs < 2; ++hs) {
      float mn[10], md[10], mx[10];
      #pragma unroll
      for (int j = 0; j < 10; ++j) {
        const int L = (hs << 3) + j;
        float a0 = COLV(0, L), a1 = COLV(1, L), a2 = COLV(2, L);
        mn[j] = min3f(a0, a1, a2);
        md[j] = med3f(a0, a1, a2);
        mx[j] = max3f(a0, a1, a2);
      }
      #pragma unroll
      for (int k = 0; k < 8; ++k) {
        float t0 = max3f(mn[k], mn[k+1], mn[k+2]);
        float t1 = med3f(md[k], md[k+1], md[k+2]);
        float t2 = min3f(mx[k], mx[k+1], mx[k+2]);
        Bt[w][(e << 4) + (hs << 3) + k][mc] = f2bf(med3f(t0, t1, t2));
      }
    }
#undef COLV

    // (4) residual fold: staged channels = oc blocks {2ks, 2ks+1};
    //     acc[d][n][q] += x[oc=n*16+l15][rw][pw+16d+4g+q] (aligned f32x4)
    #pragma unroll
    for (int d = 0; d < 2; ++d)
      #pragma unroll
      for (int nn = 0; nn < 2; ++nn) {
        const int phys = (((h << 3) + (d << 2) + g) ^ l15) << 2;
        const f32x4 xv = *(const f32x4*)&Xs[cur][((((nn << 4) + l15) << 2) + drb + 1)][phys];
        acc[d][(ks << 1) + nn] += xv;
      }

    // (5) W fragments (B-operand), all 16 oc blocks; L1-hot 16 KB slice
    bf16x8 wf[16];
    #pragma unroll
    for (int n = 0; n < 16; ++n) {
      const int fidx = (((ks << 4) + n) << 6) + lane;
      wf[n] = __builtin_bit_cast(bf16x8, *(const u16x8*)(wbf + ((size_t)fidx << 3)));
    }

    // (6) wave-private Bt: cross-lane ds_write -> ds_read needs lgkm drain only
    asm volatile("s_waitcnt lgkmcnt(0)" ::: "memory");
    __builtin_amdgcn_sched_barrier(0);

    bf16x8 pa[2];
    #pragma unroll
    for (int d = 0; d < 2; ++d)
      pa[d] = __builtin_bit_cast(bf16x8, *(const u16x8*)&Bt[w][(d << 4) + l15][g << 3]);

    // (7) MFMA: A = med (pa), B = W (wf)
    __builtin_amdgcn_s_setprio(1);
    #pragma unroll
    for (int d = 0; d < 2; ++d)
      #pragma unroll
      for (int n = 0; n < 16; ++n)
        acc[d][n] = __builtin_amdgcn_mfma_f32_16x16x32_bf16(pa[d], wf[n], acc[d][n], 0, 0, 0);
    __builtin_amdgcn_s_setprio(0);

    // (8) single per-step barrier: stage(ks+1) drained + Xs[cur] readers done
    if (ks < 7) __syncthreads();
  }

  // --- epilogue (write-only): oc = n*16+l15, px = 32h + 16d + 4g + q ---
  #pragma unroll
  for (int n = 0; n < 16; ++n) {
    const float bv = bias[(n << 4) + l15];
    const int o = (n << 4) + l15;
    #pragma unroll
    for (int d = 0; d < 2; ++d) {
      const size_t idx = ((((size_t)b << 8) + (size_t)o) << 12)
                       + ((size_t)rw << 6) + (h << 5) + (d << 4) + (g << 2);
      f32x4 res;
      #pragma unroll
      for (int q = 0; q < 4; ++q) res[q] = acc[d][n][q] + bv;
      *(f32x4*)(out + idx) = res;
    }
  }
}

extern "C" void kernel_launch(void* const* d_in, const int* in_sizes, int n_in,
                              void* d_out, int out_size, void* d_ws, size_t ws_size,
                              hipStream_t stream) {
  const float* x  = (const float*)d_in[0];
  const float* cw = (const float*)d_in[1];
  const float* cb = (const float*)d_in[2];
  float* out = (float*)d_out;
  unsigned short* wbf = (unsigned short*)d_ws;   // 128 KB fragment-linear W

  hipLaunchKernelGGL(wconv_k, dim3(32), dim3(256), 0, stream, cw, wbf);
  hipLaunchKernelGGL(fused_k, dim3(1024), dim3(256), 0, stream, x, wbf, cb, out);
}

// Round 19
// 64.715 us; speedup vs baseline: 1.3320x; 1.3320x over previous
//
#include <hip/hip_runtime.h>

typedef float f32x4 __attribute__((ext_vector_type(4)));
typedef __bf16 bf16x8 __attribute__((ext_vector_type(8)));
typedef unsigned short u16x8 __attribute__((ext_vector_type(8)));

__device__ __forceinline__ unsigned short f2bf(float f) {
  union { float f; unsigned u; } v; v.f = f;
  unsigned r = v.u + 0x7FFFu + ((v.u >> 16) & 1u);
  return (unsigned short)(r >> 16);
}

__device__ __forceinline__ float min3f(float a, float b, float c) {
  return fminf(fminf(a, b), c);
}
__device__ __forceinline__ float max3f(float a, float b, float c) {
  return fmaxf(fmaxf(a, b), c);
}
__device__ __forceinline__ float med3f(float a, float b, float c) {
  return __builtin_amdgcn_fmed3f(a, b, c);
}

// async global->LDS, 16B per lane, LDS dest = wave-uniform base + lane*16
__device__ __forceinline__ void gload_lds16(const void* g, void* l) {
  __builtin_amdgcn_global_load_lds(
      (const __attribute__((address_space(1))) void*)g,
      (__attribute__((address_space(3))) void*)l, 16, 0, 0);
}

// conv_w fp32 [256][256] -> bf16 in MFMA-fragment-linear order:
// wbf[((ks*16 + ob)*64 + lane)*8 + j] = bf16(W[ob*16 + (lane&15)][ks*32 + (lane>>4)*8 + j])
__global__ void wconv_k(const float* __restrict__ w, unsigned short* __restrict__ wbf) {
  int idx  = blockIdx.x * 256 + threadIdx.x;   // 0..8191
  int lane = idx & 63;
  int ob   = (idx >> 6) & 15;
  int ks   = idx >> 10;                        // 0..7
  int o = (ob << 4) + (lane & 15);
  int c = (ks << 5) + ((lane >> 4) << 3);
  const float* src = w + (o << 8) + c;
  f32x4 v0 = *(const f32x4*)src;
  f32x4 v1 = *(const f32x4*)(src + 4);
  u16x8 ov;
  ov[0] = f2bf(v0[0]); ov[1] = f2bf(v0[1]); ov[2] = f2bf(v0[2]); ov[3] = f2bf(v0[3]);
  ov[4] = f2bf(v1[0]); ov[5] = f2bf(v1[1]); ov[6] = f2bf(v1[2]); ov[7] = f2bf(v1[3]);
  *(u16x8*)(wbf + (idx << 3)) = ov;
}

// One block = (batch, row-pair): 128 px x 256 oc, 256 threads.
// ONE plain __syncthreads per K-step (8 barriers vs R11/R16's 15):
//   step ks: stage(ks+1)->Xs[nxt] | wf | median+fold read Xs[cur] ->
//            Bt[ks&1] | __syncthreads | pa(Bt[ks&1]) + MFMA
// Race-freedom: Xs[nxt]'s previous readers (step ks-1 medians) drained at
// barrier ks-1 (syncthreads waits lgkm per wave before release); median &
// fold read only Xs[cur] which no one writes this step; Bt parity keeps a
// slow wave's pa(ks) reads disjoint from a fast wave's median(ks+1) writes.
// LDS = Xs 64K + Bt 16K = 80 KB exactly -> 2 blocks/CU (163840 = limit).
__launch_bounds__(256, 2)
__global__ void fused_k(const float* __restrict__ x,
                        const unsigned short* __restrict__ wbf,
                        const float* __restrict__ bias,
                        float* __restrict__ out) {
  __shared__ float Xs[2][128][64];          // 64 KB: row = ci*4 + dr, px-block swizzled
  __shared__ unsigned short Bt[2][128][32]; // 16 KB: [buf][px'][c, s-XOR block swizzle]

  const int t   = threadIdx.x;
  const int blk = blockIdx.x;
  const int swz = ((blk & 7) << 7) | (blk >> 3);   // XCD-bijective (1024 = 8*128)
  const int b   = swz >> 5;
  const int r0  = (swz & 31) << 1;         // even row, rows r0 and r0+1
  const int lane = t & 63;
  const int w    = t >> 6;       // wave 0..3
  const int g    = lane >> 4;    // lane group 0..3
  const int l15  = lane & 15;

  // median task: channel ci = t>>3 (0..31), strip s = t&7 (8 px, both rows)
  const int ci  = t >> 3;
  const int s   = t & 7;
  const int px0 = s << 3;
  const int cw  = ci ^ ((s & 3) << 3);     // Bt bank-deconflict swizzle
  const bool hasL = (s > 0), hasR = (s < 7);
  const bool zTop = (r0 == 0), zBot = (r0 == 62);

  const float* xb = x + ((size_t)b << 20);   // b * 256*64*64

  float bn[4];
  #pragma unroll
  for (int n = 0; n < 4; ++n) bn[n] = bias[(w << 6) + (n << 4) + l15];

  // staging: issue p stages channel cp=8w+p, rows dr=lane>>4 (4 rows = 1 KB)
  unsigned soff[8];
  #pragma unroll
  for (int p = 0; p < 8; ++p) {
    int cp = (w << 3) + p;
    int gr = r0 + (lane >> 4) - 1;
    gr = gr < 0 ? 0 : (gr > 63 ? 63 : gr);   // clamp; zeroed in VALU at median
    int bG = (lane & 15) ^ p;                // pre-swizzle px-block by cp&7==p
    soff[p] = ((unsigned)cp << 14) + ((unsigned)gr << 8) + ((unsigned)bG << 4);
  }

  auto stage = [&](int step, int buf) {
    const unsigned kso = (unsigned)step << 19;   // step * 32ch * 16KB
    #pragma unroll
    for (int p = 0; p < 8; ++p)
      gload_lds16((const char*)xb + (soff[p] + kso), &Xs[buf][(w << 5) + (p << 2)][0]);
  };

  f32x4 acc[8][4];
  #pragma unroll
  for (int m = 0; m < 8; ++m)
    #pragma unroll
    for (int n = 0; n < 4; ++n)
      acc[m][n] = (f32x4){0.f, 0.f, 0.f, 0.f};

  stage(0, 0);
  __syncthreads();   // Xs[0] ready

  const int ri0 = ci << 2;
  const int sig = ci & 7;
  const int bA  = ((s << 1)) ^ sig;
  const int bB  = ((s << 1) | 1) ^ sig;

  #pragma unroll
  for (int ks = 0; ks < 8; ++ks) {
    const int cur = ks & 1;

    // --- stage ks+1 into Xs[cur^1]: its step-(ks-1) readers all drained at
    //     barrier ks-1 (all waves), so plain overwrite is safe. ---
    if (ks < 7) stage(ks + 1, cur ^ 1);

    // --- W fragments (L2-hot, coalesced) ---
    bf16x8 wfc[4];
    #pragma unroll
    for (int n = 0; n < 4; ++n) {
      const int fidx = (((ks << 4) + (w << 2) + n) << 6) + lane;
      wfc[n] = __builtin_bit_cast(bf16x8, *(const u16x8*)(wbf + ((size_t)fidx << 3)));
    }

    // --- median source reads: 4 rows x 2 vecs from Xs[cur] ---
    f32x4 va[4], vb[4];
    #pragma unroll
    for (int dr = 0; dr < 4; ++dr) {
      const float* rp = &Xs[cur][ri0 + dr][0];
      va[dr] = *(const f32x4*)(rp + (bA << 2));
      vb[dr] = *(const f32x4*)(rp + (bB << 2));
    }
    float le[4], re[4];
    #pragma unroll
    for (int dr = 0; dr < 4; ++dr) {
      le[dr] = __shfl_up(vb[dr][3], 1);
      re[dr] = __shfl_down(va[dr][0], 1);
    }

    // --- residual fold (reads Xs[cur] only — no writer this step): at step
    //     ks = 2w+h, staged channels ARE wave w's oc for n in {2h, 2h+1} ---
    if ((ks >> 1) == w) {
      const int h = ks & 1;
      #pragma unroll
      for (int nn = 0; nn < 2; ++nn) {
        const int n  = (h << 1) + nn;
        const int cx = (nn << 4) + l15;
        const int sx = cx & 7;
        const int rb = cx << 2;
        #pragma unroll
        for (int m = 0; m < 8; ++m) {
          const int bL = ((((m & 3) << 2) + g) ^ sx) << 2;
          const f32x4 xv = *(const f32x4*)&Xs[cur][rb + 1 + (m >> 2)][bL];
          acc[m][n] += xv;
        }
      }
    }

    // --- strip A (output row r0): staged rows 0,1,2 -> Bt[cur] ---
    {
      float R0[10], R1[10], R2[10];
      R0[0] = hasL ? le[0] : 0.f; R1[0] = hasL ? le[1] : 0.f; R2[0] = hasL ? le[2] : 0.f;
      R0[9] = hasR ? re[0] : 0.f; R1[9] = hasR ? re[1] : 0.f; R2[9] = hasR ? re[2] : 0.f;
      #pragma unroll
      for (int j = 0; j < 4; ++j) {
        R0[1 + j] = va[0][j]; R0[5 + j] = vb[0][j];
        R1[1 + j] = va[1][j]; R1[5 + j] = vb[1][j];
        R2[1 + j] = va[2][j]; R2[5 + j] = vb[2][j];
      }
      if (zTop) {
        #pragma unroll
        for (int j = 0; j < 10; ++j) R0[j] = 0.f;
      }
      float mn[10], md[10], mx[10];
      #pragma unroll
      for (int j = 0; j < 10; ++j) {
        mn[j] = min3f(R0[j], R1[j], R2[j]);
        md[j] = med3f(R0[j], R1[j], R2[j]);
        mx[j] = max3f(R0[j], R1[j], R2[j]);
      }
      #pragma unroll
      for (int i = 0; i < 8; ++i) {
        float t0 = max3f(mn[i], mn[i+1], mn[i+2]);
        float t1 = med3f(md[i], md[i+1], md[i+2]);
        float t2 = min3f(mx[i], mx[i+1], mx[i+2]);
        Bt[cur][px0 + i][cw] = f2bf(med3f(t0, t1, t2));
      }
    }
    // --- strip B (output row r0+1): staged rows 1,2,3 -> Bt[cur] ---
    {
      float R0[10], R1[10], R2[10];
      R0[0] = hasL ? le[1] : 0.f; R1[0] = hasL ? le[2] : 0.f; R2[0] = hasL ? le[3] : 0.f;
      R0[9] = hasR ? re[1] : 0.f; R1[9] = hasR ? re[2] : 0.f; R2[9] = hasR ? re[3] : 0.f;
      #pragma unroll
      for (int j = 0; j < 4; ++j) {
        R0[1 + j] = va[1][j]; R0[5 + j] = vb[1][j];
        R1[1 + j] = va[2][j]; R1[5 + j] = vb[2][j];
        R2[1 + j] = va[3][j]; R2[5 + j] = vb[3][j];
      }
      if (zBot) {
        #pragma unroll
        for (int j = 0; j < 10; ++j) R2[j] = 0.f;
      }
      float mn[10], md[10], mx[10];
      #pragma unroll
      for (int j = 0; j < 10; ++j) {
        mn[j] = min3f(R0[j], R1[j], R2[j]);
        md[j] = med3f(R0[j], R1[j], R2[j]);
        mx[j] = max3f(R0[j], R1[j], R2[j]);
      }
      #pragma unroll
      for (int i = 0; i < 8; ++i) {
        float t0 = max3f(mn[i], mn[i+1], mn[i+2]);
        float t1 = med3f(md[i], md[i+1], md[i+2]);
        float t2 = min3f(mx[i], mx[i+1], mx[i+2]);
        Bt[cur][64 + px0 + i][cw] = f2bf(med3f(t0, t1, t2));
      }
    }

    // --- THE single per-step barrier: Bt[cur] published; stage(ks+1)
    //     landed; all Xs[cur] reads drained (per-wave lgkm in syncthreads) ---
    __syncthreads();

    // --- P fragments + MFMA from Bt[cur]; a fast wave's next median
    //     writes Bt[cur^1] — disjoint from any slow wave's reads here ---
    bf16x8 pa[8];
    #pragma unroll
    for (int m = 0; m < 8; ++m) {
      const int px = (m << 4) + l15;
      const int gc = (g ^ ((px >> 3) & 3)) << 3;
      pa[m] = __builtin_bit_cast(bf16x8, *(const u16x8*)&Bt[cur][px][gc]);
    }
    #pragma unroll
    for (int m = 0; m < 8; ++m)
      #pragma unroll
      for (int n = 0; n < 4; ++n)
        acc[m][n] = __builtin_amdgcn_mfma_f32_16x16x32_bf16(pa[m], wfc[n], acc[m][n], 0, 0, 0);
  }

  // --- epilogue (write-only): px' = (m&3)*16+g*4+q, row r0+(m>>2) ---
  #pragma unroll
  for (int m = 0; m < 8; ++m) {
    #pragma unroll
    for (int n = 0; n < 4; ++n) {
      const int o = (w << 6) + (n << 4) + l15;
      const size_t idx = ((((size_t)b << 8) + (size_t)o) << 12)
                       + ((size_t)(r0 + (m >> 2)) << 6)
                       + (size_t)(((m & 3) << 4) + (g << 2));
      f32x4 res;
      #pragma unroll
      for (int q = 0; q < 4; ++q) res[q] = acc[m][n][q] + bn[n];
      *(f32x4*)(out + idx) = res;
    }
  }
}

extern "C" void kernel_launch(void* const* d_in, const int* in_sizes, int n_in,
                              void* d_out, int out_size, void* d_ws, size_t ws_size,
                              hipStream_t stream) {
  const float* x  = (const float*)d_in[0];
  const float* cw = (const float*)d_in[1];
  const float* cb = (const float*)d_in[2];
  float* out = (float*)d_out;
  unsigned short* wbf = (unsigned short*)d_ws;   // 128 KB fragment-linear W

  hipLaunchKernelGGL(wconv_k, dim3(32), dim3(256), 0, stream, cw, wbf);
  hipLaunchKernelGGL(fused_k, dim3(1024), dim3(256), 0, stream, x, wbf, cb, out);
}